// Round 7
// baseline (333.288 us; speedup 1.0000x reference)
//
#include <hip/hip_runtime.h>

#define BB 4
#define CC 3
#define HH 512
#define WW 512
#define NS 81              // 9 x 9 shifts
#define IMG (HH * WW)
#define CHW (CC * IMG)
#define STRIP 8            // rows per k_sims block
#define NSTRIP (HH / STRIP)              // 64
#define NBLK (BB * CC * NSTRIP)          // 768 blocks (all 81 shifts each)

// ws layout: float partials[NBLK][81] at byte 0 (~249 KB); int best[BB*2] after.
#define BEST_OFF (NBLK * NS * sizeof(float))

// constant-index component select (folds after full unroll)
#define C4(v, i) ((i) == 0 ? (v).x : (i) == 1 ? (v).y : (i) == 2 ? (v).z : (v).w)

// sim(b,sx,sy) = sum over c,i,j (both (i,j) and (i+sx,j+sy) in bounds) of
//               x[b,c,i,j] * x_ref[b,c,i+sx,j+sy]
// Block = (bc, 8-row strip), 576 threads = 9 waves; wave w owns sx = w-4.
// ref rows [r0-4, r0+12) staged ONCE in LDS, zero-padded +-4 cols, split into
// even/odd float4-chunk arrays (window reads are lane-stride-16B).
// R6 lesson: NO address-cast local arrays — window = 4 named float4s, FMA
// operands picked by constant-folded component selects (SROA-proof).
__global__ __launch_bounds__(576, 7) void k_sims(const float* __restrict__ xref,
                                                 const float* __restrict__ x,
                                                 float* __restrict__ partials) {
    int bid   = blockIdx.x;
    int strip = bid & (NSTRIP - 1);
    int bc    = bid >> 6;
    int r0    = strip * STRIP;
    const float* xp = x    + (size_t)bc * IMG;
    const float* rp = xref + (size_t)bc * IMG;
    int tid  = threadIdx.x;
    int lane = tid & 63;
    int wav  = tid >> 6;                 // 0..8  == sxi
    int j0   = lane << 3;                // 8 floats per lane

    // chunk c of a row covers cols [4c-4, 4c); chunk 0 and 129 are zero pads.
    // even chunks -> refE[row][c/2], odd -> refO[row][c/2].
    __shared__ float4 refE[16][65];
    __shared__ float4 refO[16][65];

    for (int idx = tid; idx < 16 * 128; idx += 576) {
        int r  = idx >> 7;               // staged row 0..15
        int gc = idx & 127;              // float4 group within row
        int g  = r0 - 4 + r;             // global ref row
        float4 v = make_float4(0.f, 0.f, 0.f, 0.f);
        if ((unsigned)g < HH) v = *(const float4*)(rp + g * WW + gc * 4);
        int k = gc + 1;                  // chunk index
        if (k & 1) refO[r][k >> 1] = v;
        else       refE[r][k >> 1] = v;
    }
    if (tid < 32) {                      // zero pads: chunk 0 and chunk 129
        float4 z = make_float4(0.f, 0.f, 0.f, 0.f);
        if (tid < 16) refE[tid][0] = z;
        else          refO[tid - 16][64] = z;
    }
    __syncthreads();

    float acc[9];
#pragma unroll
    for (int s = 0; s < 9; ++s) acc[s] = 0.f;

#pragma unroll
    for (int rr = 0; rr < STRIP; ++rr) {
        int ip = r0 + rr;                // x row (always in bounds)
        const float* xrow = xp + ip * WW + j0;
        float4 xa = *(const float4*)(xrow);       // x cols j0   .. j0+3
        float4 xb = *(const float4*)(xrow + 4);   // x cols j0+4 .. j0+7

        int lr = rr + wav;               // local ref row = rr + sx + 4, in [0,16)
        float4 c0 = refE[lr][lane];      // ref cols j0-4 .. j0-1
        float4 c1 = refO[lr][lane];      // ref cols j0   .. j0+3
        float4 c2 = refE[lr][lane + 1];  // ref cols j0+4 .. j0+7
        float4 c3 = refO[lr][lane + 1];  // ref cols j0+8 .. j0+11

#pragma unroll
        for (int syi = 0; syi < 9; ++syi) {
#pragma unroll
            for (int k = 0; k < 8; ++k) {
                int i = k + syi;         // window index 0..15 (constant)
                float wv = (i < 4)  ? C4(c0, i & 3)
                         : (i < 8)  ? C4(c1, i & 3)
                         : (i < 12) ? C4(c2, i & 3)
                         :            C4(c3, i & 3);
                float xv = (k < 4) ? C4(xa, k & 3) : C4(xb, k & 3);
                acc[syi] += xv * wv;
            }
        }
    }

    // wave reduce (fp32); lane 0 stores its wave's 9 sy-slots directly.
#pragma unroll
    for (int s = 0; s < 9; ++s) {
        float v = acc[s];
        for (int off = 32; off; off >>= 1) v += __shfl_down(v, off, 64);
        if (lane == 0) partials[bid * NS + wav * 9 + s] = v;
    }
}

// One block (512 threads) per batch: parallel fp64 reduce of the 192 partials
// per shift-slot (6 threads/slot, 32 independent loads each), then argmax with
// first-index tie-break (strict > keeps lowest index).
__global__ __launch_bounds__(512) void k_argmax(const float* __restrict__ partials,
                                                int* __restrict__ best,
                                                float* __restrict__ outTail) {
    int b = blockIdx.x;
    int t = threadIdx.x;
    __shared__ double lds[486];
    __shared__ double vals[NS];
    if (t < 486) {
        int slot = t / 6;                 // 0..80
        int sub  = t % 6;
        double acc = 0.0;
#pragma unroll 8
        for (int k = 0; k < 32; ++k) {
            int q  = sub * 32 + k;        // q in [0, 192)
            int c  = q >> 6;              // q / 64
            int st = q & 63;              // q % 64
            int pb = (b * CC + c) * NSTRIP + st;
            acc += (double)partials[pb * NS + slot];
        }
        lds[t] = acc;
    }
    __syncthreads();
    if (t < NS) {
        double s = 0.0;
#pragma unroll
        for (int k = 0; k < 6; ++k) s += lds[t * 6 + k];
        vals[t] = s;
    }
    __syncthreads();
    if (t == 0) {
        double bv = vals[0];
        int bi = 0;
        for (int s = 1; s < NS; ++s)
            if (vals[s] > bv) { bv = vals[s]; bi = s; }
        int sx = bi / 9 - 4;
        int sy = bi % 9 - 4;
        best[b * 2]     = sx;
        best[b * 2 + 1] = sy;
        outTail[b * 2]     = (float)sx;
        outTail[b * 2 + 1] = (float)sy;
    }
}

// out[b,c,i,j] = in-bounds(i-sx, j-sy) ? x[b,c,i-sx,j-sy] : 0
// One block = 2 rows of one (b,c) image; fast path = offset float4 load.
__global__ __launch_bounds__(256) void k_apply(const float* __restrict__ x,
                                               const int* __restrict__ best,
                                               float* __restrict__ out) {
    int blk = blockIdx.x;
    int bc  = blk >> 8;                 // 256 blocks per image (512 rows / 2)
    int tid = threadIdx.x;
    int row = ((blk & 255) << 1) + (tid >> 7);
    int j0  = (tid & 127) << 2;
    int b   = bc / CC;                  // block-uniform -> scalar loads of best
    int sx  = best[b * 2];
    int sy  = best[b * 2 + 1];
    int is  = row - sx;
    float4 v = make_float4(0.f, 0.f, 0.f, 0.f);
    if ((unsigned)is < HH) {
        const float* src = x + (size_t)bc * IMG + is * WW;
        int js0 = j0 - sy;
        if (js0 >= 0 && js0 + 3 < WW) {
            v = *(const float4*)(src + js0);   // 4B-aligned dwordx4, exact (R2-R6)
        } else {
            float* vv = (float*)&v;
#pragma unroll
            for (int k = 0; k < 4; ++k) {
                int js = js0 + k;
                if ((unsigned)js < WW) vv[k] = src[js];
            }
        }
    }
    *(float4*)(out + (size_t)bc * IMG + row * WW + j0) = v;
}

extern "C" void kernel_launch(void* const* d_in, const int* in_sizes, int n_in,
                              void* d_out, int out_size, void* d_ws, size_t ws_size,
                              hipStream_t stream) {
    const float* xref = (const float*)d_in[0];
    const float* x    = (const float*)d_in[1];
    float* out = (float*)d_out;

    float* partials = (float*)d_ws;
    int*   best     = (int*)((char*)d_ws + BEST_OFF);

    k_sims<<<NBLK, 576, 0, stream>>>(xref, x, partials);

    k_argmax<<<BB, 512, 0, stream>>>(partials, best, out + (size_t)BB * CHW);

    int applyBlocks = (BB * CC * HH) / 2;   // 3072
    k_apply<<<applyBlocks, 256, 0, stream>>>(x, best, out);
}

// Round 8
// 109.171 us; speedup vs baseline: 3.0529x; 3.0529x over previous
//
#include <hip/hip_runtime.h>

#define BB 4
#define CC 3
#define HH 512
#define WW 512
#define NS 81              // 9 x 9 shifts
#define IMG (HH * WW)
#define CHW (CC * IMG)
#define STRIP 32           // rows per k_sims block (8 rows per wave)
#define NSTRIP (HH / STRIP)              // 16
#define NBLK (BB * CC * NSTRIP * 9)      // 1728 blocks (one sx each)

// ws layout: float partials[NBLK][9] at byte 0 (~62 KB); int best[BB*2] after.
#define BEST_OFF (NBLK * 9 * sizeof(float))

// constant-index component select (folds after full unroll)
#define C4(v, i) ((i) == 0 ? (v).x : (i) == 1 ? (v).y : (i) == 2 ? (v).z : (v).w)

// sim(b,sx,sy) = sum over c,i,j (both (i,j) and (i+sx,j+sy) in bounds) of
//               x[b,c,i,j] * x_ref[b,c,i+sx,j+sy]
// R5 skeleton (256 thr — the only config proven spill-free) + two fixes:
//  (a) ALL global loads aligned float4; the +-4 col window halo comes from
//      one-lane __shfl ops (lane-0/63 zero masks == the column mask).
//  (b) launch_bounds(256,4): VGPR cap 128 so the unrolled 8-iter loop can
//      pipeline loads (R5's (256,8) cap 64 forced a serial load->FMA chain).
__global__ __launch_bounds__(256, 4) void k_sims(const float* __restrict__ xref,
                                                 const float* __restrict__ x,
                                                 float* __restrict__ partials) {
    int bid  = blockIdx.x;
    int sxi  = bid % 9;                  // sx = sxi - 4
    int tmp  = bid / 9;
    int strip = tmp % NSTRIP;
    int bc   = tmp / NSTRIP;
    const float* xp = x    + (size_t)bc * IMG;
    const float* rp = xref + (size_t)bc * IMG;
    int tid  = threadIdx.x;
    int lane = tid & 63;
    int wave = tid >> 6;
    int j0   = lane << 3;                // 8 floats per lane
    int sx   = sxi - 4;
    int ip0  = strip * STRIP + wave * 8;

    float acc[9];
#pragma unroll
    for (int s = 0; s < 9; ++s) acc[s] = 0.f;

#pragma unroll
    for (int rr = 0; rr < 8; ++rr) {
        int ip = ip0 + rr;               // x row (always in bounds)
        int ii = ip + sx;                // ref row (wave-uniform test)
        if ((unsigned)ii >= HH) continue;

        const float* xrow = xp + ip * WW + j0;
        const float* rrow = rp + ii * WW + j0;
        float4 xa = *(const float4*)(xrow);        // x   cols j0   .. j0+3
        float4 xb = *(const float4*)(xrow + 4);    // x   cols j0+4 .. j0+7
        float4 ra = *(const float4*)(rrow);        // ref cols j0   .. j0+3
        float4 rb = *(const float4*)(rrow + 4);    // ref cols j0+4 .. j0+7

        // halo: prev4 = ref cols j0-4..j0-1 (lane-1's rb), next4 = j0+8..j0+11
        float p0 = __shfl_up(rb.x, 1, 64);
        float p1 = __shfl_up(rb.y, 1, 64);
        float p2 = __shfl_up(rb.z, 1, 64);
        float p3 = __shfl_up(rb.w, 1, 64);
        if (lane == 0) { p0 = p1 = p2 = p3 = 0.f; }   // cols < 0 -> mask
        float n0 = __shfl_down(ra.x, 1, 64);
        float n1 = __shfl_down(ra.y, 1, 64);
        float n2 = __shfl_down(ra.z, 1, 64);
        float n3 = __shfl_down(ra.w, 1, 64);
        if (lane == 63) { n0 = n1 = n2 = n3 = 0.f; }  // cols >= 512 -> mask

#define P4(i) ((i) == 0 ? p0 : (i) == 1 ? p1 : (i) == 2 ? p2 : p3)
#define N4(i) ((i) == 0 ? n0 : (i) == 1 ? n1 : (i) == 2 ? n2 : n3)
#pragma unroll
        for (int syi = 0; syi < 9; ++syi) {
#pragma unroll
            for (int k = 0; k < 8; ++k) {
                int i = k + syi;         // window index 0..15 (constant)
                float wv = (i < 4)  ? P4(i)
                         : (i < 8)  ? C4(ra, i - 4)
                         : (i < 12) ? C4(rb, i - 8)
                         :            N4(i - 12);
                float xv = (k < 4) ? C4(xa, k) : C4(xb, k - 4);
                acc[syi] += xv * wv;
            }
        }
#undef P4
#undef N4
    }

    // wave reduce (fp32), block combine in LDS, direct store (no atomics)
    __shared__ float part[4][9];
#pragma unroll
    for (int s = 0; s < 9; ++s) {
        float v = acc[s];
        for (int off = 32; off; off >>= 1) v += __shfl_down(v, off, 64);
        if (lane == 0) part[wave][s] = v;
    }
    __syncthreads();
    if (tid < 9)
        partials[bid * 9 + tid] = part[0][tid] + part[1][tid]
                                + part[2][tid] + part[3][tid];
}

// One block (512 threads) per batch: parallel fp64 reduce of the 48 partials
// per shift-slot (6 threads/slot, 8 independent loads each), then argmax with
// first-index tie-break (strict > keeps lowest index).
__global__ __launch_bounds__(512) void k_argmax(const float* __restrict__ partials,
                                                int* __restrict__ best,
                                                float* __restrict__ outTail) {
    int b = blockIdx.x;
    int t = threadIdx.x;
    __shared__ double lds[486];
    __shared__ double vals[NS];
    if (t < 486) {
        int slot = t / 6;                 // 0..80
        int sub  = t % 6;
        int sxi = slot / 9, syi = slot % 9;
        double acc = 0.0;
#pragma unroll
        for (int k = 0; k < 8; ++k) {     // 8 values each
            int q  = sub * 8 + k;         // q in [0, 48)
            int c  = q >> 4;              // q / 16
            int st = q & 15;              // q % 16
            int pb = ((b * CC + c) * NSTRIP + st) * 9 + sxi;
            acc += (double)partials[pb * 9 + syi];
        }
        lds[t] = acc;
    }
    __syncthreads();
    if (t < NS) {
        double s = 0.0;
#pragma unroll
        for (int k = 0; k < 6; ++k) s += lds[t * 6 + k];
        vals[t] = s;
    }
    __syncthreads();
    if (t == 0) {
        double bv = vals[0];
        int bi = 0;
        for (int s = 1; s < NS; ++s)
            if (vals[s] > bv) { bv = vals[s]; bi = s; }
        int sx = bi / 9 - 4;
        int sy = bi % 9 - 4;
        best[b * 2]     = sx;
        best[b * 2 + 1] = sy;
        outTail[b * 2]     = (float)sx;
        outTail[b * 2 + 1] = (float)sy;
    }
}

// out[b,c,i,j] = in-bounds(i-sx, j-sy) ? x[b,c,i-sx,j-sy] : 0
// One block = 2 rows of one (b,c) image; fast path = offset float4 load.
__global__ __launch_bounds__(256) void k_apply(const float* __restrict__ x,
                                               const int* __restrict__ best,
                                               float* __restrict__ out) {
    int blk = blockIdx.x;
    int bc  = blk >> 8;                 // 256 blocks per image (512 rows / 2)
    int tid = threadIdx.x;
    int row = ((blk & 255) << 1) + (tid >> 7);
    int j0  = (tid & 127) << 2;
    int b   = bc / CC;                  // block-uniform -> scalar loads of best
    int sx  = best[b * 2];
    int sy  = best[b * 2 + 1];
    int is  = row - sx;
    float4 v = make_float4(0.f, 0.f, 0.f, 0.f);
    if ((unsigned)is < HH) {
        const float* src = x + (size_t)bc * IMG + is * WW;
        int js0 = j0 - sy;
        if (js0 >= 0 && js0 + 3 < WW) {
            v = *(const float4*)(src + js0);   // 4B-aligned dwordx4, exact (R2-R7)
        } else {
            float* vv = (float*)&v;
#pragma unroll
            for (int k = 0; k < 4; ++k) {
                int js = js0 + k;
                if ((unsigned)js < WW) vv[k] = src[js];
            }
        }
    }
    *(float4*)(out + (size_t)bc * IMG + row * WW + j0) = v;
}

extern "C" void kernel_launch(void* const* d_in, const int* in_sizes, int n_in,
                              void* d_out, int out_size, void* d_ws, size_t ws_size,
                              hipStream_t stream) {
    const float* xref = (const float*)d_in[0];
    const float* x    = (const float*)d_in[1];
    float* out = (float*)d_out;

    float* partials = (float*)d_ws;
    int*   best     = (int*)((char*)d_ws + BEST_OFF);

    k_sims<<<NBLK, 256, 0, stream>>>(xref, x, partials);

    k_argmax<<<BB, 512, 0, stream>>>(partials, best, out + (size_t)BB * CHW);

    int applyBlocks = (BB * CC * HH) / 2;   // 3072
    k_apply<<<applyBlocks, 256, 0, stream>>>(x, best, out);
}